// Round 1
// baseline (376.308 us; speedup 1.0000x reference)
//
#include <hip/hip_runtime.h>

// Problem constants: B=2, L=2048, D=1024, H=16, DH=64, BH=B*H=32, M=B*L=4096
// SCALE = DH^-0.5 = 0.125 (exact power of two -> folded into Q at projection time)

typedef __attribute__((ext_vector_type(8))) short short8;
typedef __attribute__((ext_vector_type(8))) __bf16 bf16x8;
typedef __attribute__((ext_vector_type(4))) float f32x4;

#define GLDS16(gp, lp)                                                         \
  __builtin_amdgcn_global_load_lds(                                            \
      (const __attribute__((address_space(1))) void*)(gp),                     \
      (__attribute__((address_space(3))) void*)(lp), 16, 0, 0)

__device__ __forceinline__ unsigned short f2bf(float f) {
  unsigned u = __builtin_bit_cast(unsigned, f);
  u += 0x7fffu + ((u >> 16) & 1u);   // RNE
  return (unsigned short)(u >> 16);
}

// ---------------- fused fp32 -> bf16 conversion ----------------
// x -> xb [4096][1024]; Wq|Wk|Wv -> wqkv [3072][1024]; Wo -> wob [1024][1024]
__global__ __launch_bounds__(256) void convert_all(
    const float* __restrict__ x, const float* __restrict__ wq,
    const float* __restrict__ wk, const float* __restrict__ wv,
    const float* __restrict__ wo, unsigned short* __restrict__ xb,
    unsigned short* __restrict__ wqkv, unsigned short* __restrict__ wob) {
  const int X4 = (2 * 2048 * 1024) / 4;  // 1048576 float4s of x
  const int W4 = (1024 * 1024) / 4;      // 262144 per weight
  const int total = X4 + 4 * W4;
  for (int i = blockIdx.x * 256 + threadIdx.x; i < total;
       i += gridDim.x * 256) {
    const float* src; unsigned short* dst; int off;
    if (i < X4)               { src = x;  dst = xb;                   off = i; }
    else if (i < X4 + W4)     { src = wq; dst = wqkv;                 off = i - X4; }
    else if (i < X4 + 2 * W4) { src = wk; dst = wqkv + 1024 * 1024;   off = i - X4 - W4; }
    else if (i < X4 + 3 * W4) { src = wv; dst = wqkv + 2 * 1024 * 1024; off = i - X4 - 2 * W4; }
    else                      { src = wo; dst = wob;                  off = i - X4 - 3 * W4; }
    float4 v = ((const float4*)src)[off];
    uint2 o;
    o.x = (unsigned)f2bf(v.x) | ((unsigned)f2bf(v.y) << 16);
    o.y = (unsigned)f2bf(v.z) | ((unsigned)f2bf(v.w) << 16);
    ((uint2*)dst)[off] = o;
  }
}

// ---------------- 128x128 bf16 GEMM, C = A * B^T (m97 structure) ----------------
// A [M][1024] bf16 row-major, Bw [N][1024] bf16 row-major (i.e. B^T input).
// MODE 0: QKV epilogue -> scatter to q (x0.125), k as [BH][L][DH], v as V^T [BH][DH][L]
// MODE 1: out-projection epilogue -> fp32 out[m][n] = acc + bias[n]
template <int MODE>
__global__ __launch_bounds__(256, 2) void gemm_bt(
    const unsigned short* __restrict__ A, const unsigned short* __restrict__ Bw,
    unsigned short* __restrict__ o_q, unsigned short* __restrict__ o_k,
    unsigned short* __restrict__ o_vT, const float* __restrict__ bias,
    float* __restrict__ o_f) {
  constexpr int K = 1024;
  __shared__ unsigned short As[128 * 32];
  __shared__ unsigned short Bs[128 * 32];
  const int t = threadIdx.x;
  const int w = t >> 6;            // wave 0..3
  const int lane = t & 63;
  const int g = lane >> 4;         // lane group 0..3
  const int q16 = lane & 15;
  const int wm = w >> 1, wn = w & 1;
  const int bn0 = blockIdx.x * 128, bm0 = blockIdx.y * 128;
  const int arow = t >> 2;         // 0..63 (staging row within half-tile)
  const int acol = (t & 3) * 8;    // short offset within 64B row

  f32x4 acc[4][4];
  const f32x4 z4 = {0.f, 0.f, 0.f, 0.f};
#pragma unroll
  for (int i = 0; i < 4; ++i)
#pragma unroll
    for (int j = 0; j < 4; ++j) acc[i][j] = z4;

  for (int k0 = 0; k0 < K; k0 += 32) {
#pragma unroll
    for (int c = 0; c < 2; ++c) {
      GLDS16(A + (size_t)(bm0 + c * 64 + arow) * K + k0 + acol,
             As + c * 2048 + w * 512);
      GLDS16(Bw + (size_t)(bn0 + c * 64 + arow) * K + k0 + acol,
             Bs + c * 2048 + w * 512);
    }
    __syncthreads();  // drains vmcnt -> LDS tiles ready
    bf16x8 af[4], bf[4];
#pragma unroll
    for (int i = 0; i < 4; ++i)
      af[i] = *(const bf16x8*)(As + (wm * 64 + i * 16 + q16) * 32 + g * 8);
#pragma unroll
    for (int j = 0; j < 4; ++j)
      bf[j] = *(const bf16x8*)(Bs + (wn * 64 + j * 16 + q16) * 32 + g * 8);
#pragma unroll
    for (int i = 0; i < 4; ++i)
#pragma unroll
      for (int j = 0; j < 4; ++j)
        acc[i][j] =
            __builtin_amdgcn_mfma_f32_16x16x32_bf16(af[i], bf[j], acc[i][j], 0, 0, 0);
    __syncthreads();  // all waves done reading before next stage overwrites
  }

  if constexpr (MODE == 0) {
    const int which = bn0 >> 10;  // 0=q 1=k 2=v (BN=128 divides 1024)
#pragma unroll
    for (int i = 0; i < 4; ++i)
#pragma unroll
      for (int j = 0; j < 4; ++j)
#pragma unroll
        for (int r = 0; r < 4; ++r) {
          const int m = bm0 + wm * 64 + i * 16 + g * 4 + r;   // (b,l)
          const int n = (bn0 & 1023) + wn * 64 + j * 16 + q16; // e within Wq/Wk/Wv
          const float v = acc[i][j][r];
          const int bb = m >> 11, lp = m & 2047;
          const int h = n >> 6, d = n & 63;
          const int bh = bb * 16 + h;
          if (which == 0)
            o_q[((size_t)bh * 2048 + lp) * 64 + d] = f2bf(v * 0.125f);
          else if (which == 1)
            o_k[((size_t)bh * 2048 + lp) * 64 + d] = f2bf(v);
          else
            o_vT[((size_t)bh * 64 + d) * 2048 + lp] = f2bf(v);
        }
  } else {
#pragma unroll
    for (int i = 0; i < 4; ++i)
#pragma unroll
      for (int j = 0; j < 4; ++j)
#pragma unroll
        for (int r = 0; r < 4; ++r) {
          const int m = bm0 + wm * 64 + i * 16 + g * 4 + r;
          const int n = bn0 + wn * 64 + j * 16 + q16;
          o_f[(size_t)m * 1024 + n] = acc[i][j][r] + bias[n];
        }
  }
}

// ---------------- flash attention ----------------
// grid = 32 heads * 32 q-tiles; block = 4 independent waves, each owns 16 q-rows.
// Swapped QK^T: S = mfma(K,Q) -> lane: q = lane&15 (col), kv = 4*(lane>>4)+reg (row)
// so softmax row-reduce needs only shfl_xor(16|32). P goes through a small padded
// LDS tile to become the PV A-fragment. K/V read straight from L2 (256KB/head).
__global__ __launch_bounds__(256, 2) void attn_kernel(
    const unsigned short* __restrict__ qb, const unsigned short* __restrict__ kb,
    const unsigned short* __restrict__ vT, const float* __restrict__ mask,
    unsigned short* __restrict__ hb) {
  __shared__ unsigned short Plds[4][16][40];  // per-wave [16 q][32 kv] bf16, rows padded to 80B
  const int bid = blockIdx.x;
  const int bh = bid >> 5, qt = bid & 31;
  const int t = threadIdx.x, w = t >> 6, lane = t & 63;
  const int g = lane >> 4, q16 = lane & 15;
  const int qrow = qt * 64 + w * 16;

  const unsigned short* qptr = qb + ((size_t)bh * 2048 + qrow + q16) * 64 + g * 8;
  bf16x8 qf0 = *(const bf16x8*)(qptr);        // d 0..31 slice
  bf16x8 qf1 = *(const bf16x8*)(qptr + 32);   // d 32..63 slice

  f32x4 O[4];
  const f32x4 z4 = {0.f, 0.f, 0.f, 0.f};
#pragma unroll
  for (int dt = 0; dt < 4; ++dt) O[dt] = z4;
  float mrun = -1e30f, lsum = 0.f;

  const float* mrow = mask + ((size_t)bh * 2048 + qrow + q16) * 2048 + g * 4;
  const unsigned short* kbase = kb + ((size_t)bh * 2048 + q16) * 64 + g * 8;
  const unsigned short* vbase = vT + (size_t)bh * 64 * 2048 + g * 8;

  for (int kvb = 0; kvb < 2048; kvb += 32) {
    const unsigned short* kp = kbase + (size_t)kvb * 64;
    bf16x8 kf00 = *(const bf16x8*)(kp);                // kv 0..15, d 0..31
    bf16x8 kf01 = *(const bf16x8*)(kp + 32);           // kv 0..15, d 32..63
    bf16x8 kf10 = *(const bf16x8*)(kp + 1024);         // kv 16..31, d 0..31
    bf16x8 kf11 = *(const bf16x8*)(kp + 1024 + 32);

    f32x4 S0 = z4, S1 = z4;
    S0 = __builtin_amdgcn_mfma_f32_16x16x32_bf16(kf00, qf0, S0, 0, 0, 0);
    S0 = __builtin_amdgcn_mfma_f32_16x16x32_bf16(kf01, qf1, S0, 0, 0, 0);
    S1 = __builtin_amdgcn_mfma_f32_16x16x32_bf16(kf10, qf0, S1, 0, 0, 0);
    S1 = __builtin_amdgcn_mfma_f32_16x16x32_bf16(kf11, qf1, S1, 0, 0, 0);

    f32x4 mk0 = *(const f32x4*)(mrow + kvb);
    f32x4 mk1 = *(const f32x4*)(mrow + kvb + 16);
    S0 += mk0;
    S1 += mk1;

    // online softmax (per q-row; row spread across 4 lane groups x 8 regs)
    float pm = fmaxf(fmaxf(fmaxf(S0[0], S0[1]), fmaxf(S0[2], S0[3])),
                     fmaxf(fmaxf(S1[0], S1[1]), fmaxf(S1[2], S1[3])));
    pm = fmaxf(pm, __shfl_xor(pm, 16));
    pm = fmaxf(pm, __shfl_xor(pm, 32));
    const float mnew = fmaxf(mrun, pm);
    const float alpha = __expf(mrun - mnew);
    float p0[4], p1[4];
    float rs = 0.f;
#pragma unroll
    for (int r = 0; r < 4; ++r) {
      p0[r] = __expf(S0[r] - mnew);
      p1[r] = __expf(S1[r] - mnew);
      rs += p0[r] + p1[r];
    }
    rs += __shfl_xor(rs, 16);
    rs += __shfl_xor(rs, 32);
    lsum = lsum * alpha + rs;
    mrun = mnew;

    // rescale O (O rows are q = 4g+r -> broadcast alpha from lane q')
    float ar[4];
#pragma unroll
    for (int r = 0; r < 4; ++r) ar[r] = __shfl(alpha, g * 4 + r);
#pragma unroll
    for (int dt = 0; dt < 4; ++dt)
#pragma unroll
      for (int r = 0; r < 4; ++r) O[dt][r] *= ar[r];

    // P -> LDS (bf16), then re-read as PV A-fragment
    uint2 pw0, pw1;
    pw0.x = (unsigned)f2bf(p0[0]) | ((unsigned)f2bf(p0[1]) << 16);
    pw0.y = (unsigned)f2bf(p0[2]) | ((unsigned)f2bf(p0[3]) << 16);
    pw1.x = (unsigned)f2bf(p1[0]) | ((unsigned)f2bf(p1[1]) << 16);
    pw1.y = (unsigned)f2bf(p1[2]) | ((unsigned)f2bf(p1[3]) << 16);
    *(uint2*)&Plds[w][q16][g * 4] = pw0;
    *(uint2*)&Plds[w][q16][16 + g * 4] = pw1;
    bf16x8 pf = *(const bf16x8*)&Plds[w][q16][g * 8];  // same-wave LDS ops are in order

    const unsigned short* vp = vbase + kvb;
#pragma unroll
    for (int dt = 0; dt < 4; ++dt) {
      bf16x8 vf = *(const bf16x8*)(vp + (size_t)(dt * 16 + q16) * 2048);
      O[dt] = __builtin_amdgcn_mfma_f32_16x16x32_bf16(pf, vf, O[dt], 0, 0, 0);
    }
  }

  float li[4];
#pragma unroll
  for (int r = 0; r < 4; ++r) li[r] = 1.f / __shfl(lsum, g * 4 + r);
  const int b = bh >> 4, h = bh & 15;
#pragma unroll
  for (int dt = 0; dt < 4; ++dt)
#pragma unroll
    for (int r = 0; r < 4; ++r) {
      const int qg = qrow + g * 4 + r;
      hb[((size_t)b * 2048 + qg) * 1024 + h * 64 + dt * 16 + q16] =
          f2bf(O[dt][r] * li[r]);
    }
}

extern "C" void kernel_launch(void* const* d_in, const int* in_sizes, int n_in,
                              void* d_out, int out_size, void* d_ws,
                              size_t ws_size, hipStream_t stream) {
  const float* x    = (const float*)d_in[0];
  const float* mask = (const float*)d_in[1];
  const float* wq   = (const float*)d_in[2];
  const float* wk   = (const float*)d_in[3];
  const float* wv   = (const float*)d_in[4];
  const float* wo   = (const float*)d_in[5];
  const float* bo   = (const float*)d_in[6];
  float* out = (float*)d_out;
  char* ws = (char*)d_ws;

  // workspace layout (48 MiB total)
  unsigned short* xb   = (unsigned short*)(ws);                        // 8 MiB
  unsigned short* wqkv = (unsigned short*)(ws + 8u * 1024 * 1024);     // 6 MiB
  unsigned short* wob  = (unsigned short*)(ws + 14u * 1024 * 1024);    // 2 MiB
  unsigned short* qbuf = (unsigned short*)(ws + 16u * 1024 * 1024);    // 8 MiB
  unsigned short* kbuf = (unsigned short*)(ws + 24u * 1024 * 1024);    // 8 MiB
  unsigned short* vTb  = (unsigned short*)(ws + 32u * 1024 * 1024);    // 8 MiB
  unsigned short* hb   = (unsigned short*)(ws + 40u * 1024 * 1024);    // 8 MiB
  (void)in_sizes; (void)n_in; (void)out_size; (void)ws_size;

  convert_all<<<2048, 256, 0, stream>>>(x, wq, wk, wv, wo, xb, wqkv, wob);
  gemm_bt<0><<<dim3(24, 32), 256, 0, stream>>>(xb, wqkv, qbuf, kbuf, vTb,
                                               nullptr, nullptr);
  attn_kernel<<<1024, 256, 0, stream>>>(qbuf, kbuf, vTb, mask, hb);
  gemm_bt<1><<<dim3(8, 32), 256, 0, stream>>>(hb, wob, nullptr, nullptr,
                                              nullptr, bo, out);
}